// Round 8
// baseline (35.164 us; speedup 1.0000x reference)
//
#include <hip/hip_runtime.h>

#define DEVFN __device__ __forceinline__

typedef float f32x4 __attribute__((ext_vector_type(4)));

DEVFN float min3f(float a, float b, float c) { return fminf(fminf(a, b), c); }
DEVFN float max3f(float a, float b, float c) { return fmaxf(fmaxf(a, b), c); }
DEVFN float med3f(float a, float b, float c) {
    return fmaxf(fminf(a, b), fminf(fmaxf(a, b), c));
}

// Fixed shape: 16 x 3 x 512 x 512 f32, 3x3 median (zero pad) + cover copy.
//
// One WAVE owns a full 512-wide x 4-row band. Lane i owns TWO 4-col groups:
// A = cols [4i, 4i+4)  and  B = cols [256+4i, 256+4i+4).  Every VMEM op is a
// fully wave-contiguous 1 KB transaction (lane stride 16 B). ALL horizontal
// halos come from cross-lane shuffles of edge registers:
//   col 4i-1   = lane i-1's A.w   (shfl_up),   lane 0  -> zero pad (x=-1)
//   col 4i+4   = lane i+1's A.x   (shfl_down), lane 63 -> B.x of lane 0 (seam)
//   col 256+4i-1 = lane i-1's B.w (shfl_up),   lane 0  -> A.w of lane 63 (seam)
//   col 256+4i+4 = lane i+1's B.x (shfl_down), lane 63 -> zero pad (x=512)
// -> zero halo gather loads; 36 VMEM ops per 32 px (was 30 per 16 px).
// XCD-chunked swizzle keeps vertical halo rows in the same XCD's L2.
__global__ __launch_bounds__(256) void median3x3_w8(
        const float* __restrict__ in, const float* __restrict__ cover,
        float* __restrict__ out, float* __restrict__ out2, int chunk) {
    constexpr int H = 512;

    int bid = blockIdx.x;
    int swz = (bid & 7) * chunk + (bid >> 3);          // bijective: grid%8==0
    int band = swz * (int)(blockDim.x >> 6) + (int)(threadIdx.x >> 6);
    int lane = threadIdx.x & 63;

    int plane = band >> 7;                             // 128 bands per plane
    int y0    = (band & 127) << 2;                     // first output row
    int xA    = lane << 2;

    long base = ((long)plane << 18) + ((long)y0 << 9) + xA;   // (y0, xA)
    const float* rowp = in + base;

    // rows y0-1 .. y0+4 for both column groups
    f32x4 A[6], B[6];
    #pragma unroll
    for (int t = 0; t < 4; ++t) {
        const float* rp = rowp + (t << 9);
        A[t + 1] = *reinterpret_cast<const f32x4*>(rp);
        B[t + 1] = *reinterpret_cast<const f32x4*>(rp + 256);
    }
    if (y0 > 0) {
        A[0] = *reinterpret_cast<const f32x4*>(rowp - 512);
        B[0] = *reinterpret_cast<const f32x4*>(rowp - 512 + 256);
    } else { A[0] = (f32x4)0.0f; B[0] = (f32x4)0.0f; }
    if (y0 + 4 < H) {
        A[5] = *reinterpret_cast<const f32x4*>(rowp + (4 << 9));
        B[5] = *reinterpret_cast<const f32x4*>(rowp + (4 << 9) + 256);
    } else { A[5] = (f32x4)0.0f; B[5] = (f32x4)0.0f; }

    // per-row horizontal halos via cross-lane shuffle (LDS pipe, no VMEM)
    float hlA[6], hrA[6], hlB[6], hrB[6];
    #pragma unroll
    for (int r = 0; r < 6; ++r) {
        float seamL = __shfl(A[r].w, 63);   // col 255 -> lane 0's hlB
        float seamR = __shfl(B[r].x, 0);    // col 256 -> lane 63's hrA
        float ua = __shfl_up(A[r].w, 1);
        float da = __shfl_down(A[r].x, 1);
        float ub = __shfl_up(B[r].w, 1);
        float db = __shfl_down(B[r].x, 1);
        hlA[r] = (lane == 0)  ? 0.0f  : ua;
        hrA[r] = (lane == 63) ? seamR : da;
        hlB[r] = (lane == 0)  ? seamL : ub;
        hrB[r] = (lane == 63) ? 0.0f  : db;
    }

    #pragma unroll
    for (int t = 0; t < 4; ++t) {
        // cover pass-through for this row (contiguous, issued early in iter)
        const float* cp = cover + base + (t << 9);
        f32x4 cvA = *reinterpret_cast<const f32x4*>(cp);
        f32x4 cvB = *reinterpret_cast<const f32x4*>(cp + 256);

        f32x4 oA, oB;
        #pragma unroll
        for (int grp = 0; grp < 2; ++grp) {
            float cmn[6], cmd[6], cmx[6];
            #pragma unroll
            for (int j = 0; j < 6; ++j) {
                float p, q, s;
                if (grp == 0) {
                    p = (j == 0) ? hlA[t]     : (j == 5) ? hrA[t]     : A[t][j - 1];
                    q = (j == 0) ? hlA[t + 1] : (j == 5) ? hrA[t + 1] : A[t + 1][j - 1];
                    s = (j == 0) ? hlA[t + 2] : (j == 5) ? hrA[t + 2] : A[t + 2][j - 1];
                } else {
                    p = (j == 0) ? hlB[t]     : (j == 5) ? hrB[t]     : B[t][j - 1];
                    q = (j == 0) ? hlB[t + 1] : (j == 5) ? hrB[t + 1] : B[t + 1][j - 1];
                    s = (j == 0) ? hlB[t + 2] : (j == 5) ? hrB[t + 2] : B[t + 2][j - 1];
                }
                cmn[j] = min3f(p, q, s);
                cmx[j] = max3f(p, q, s);
                cmd[j] = med3f(p, q, s);
            }
            #pragma unroll
            for (int i = 0; i < 4; ++i) {
                float lo = max3f(cmn[i], cmn[i + 1], cmn[i + 2]);
                float hi = min3f(cmx[i], cmx[i + 1], cmx[i + 2]);
                float mi = med3f(cmd[i], cmd[i + 1], cmd[i + 2]);
                float r  = med3f(lo, mi, hi);
                if (grp == 0) oA[i] = r; else oB[i] = r;
            }
        }
        float* op = out + base + (t << 9);
        __builtin_nontemporal_store(oA, reinterpret_cast<f32x4*>(op));
        __builtin_nontemporal_store(oB, reinterpret_cast<f32x4*>(op + 256));
        float* o2 = out2 + base + (t << 9);
        __builtin_nontemporal_store(cvA, reinterpret_cast<f32x4*>(o2));
        __builtin_nontemporal_store(cvB, reinterpret_cast<f32x4*>(o2 + 256));
    }
}

extern "C" void kernel_launch(void* const* d_in, const int* in_sizes, int n_in,
                              void* d_out, int out_size, void* d_ws, size_t ws_size,
                              hipStream_t stream) {
    const float* noised = (const float*)d_in[0];
    const float* cover  = (const float*)d_in[1];
    float* out = (float*)d_out;

    const int n = in_sizes[0];                 // 16*3*512*512 = 12582912
    const int rows_total = n / 512;            // 24576
    const int bands = rows_total / 4;          // 6144 waves
    const int block = 256;                     // 4 bands per block
    const int grid = bands / 4;                // 1536 (divisible by 8)
    const int chunk = grid / 8;                // 192

    median3x3_w8<<<grid, block, 0, stream>>>(noised, cover, out, out + n, chunk);
}